// Round 10
// baseline (453.964 us; speedup 1.0000x reference)
//
#include <hip/hip_runtime.h>
#include <cmath>

#define L_DIM 2048
#define C_CH  16
#define B_SZ  2
#define N_G   4
#define C_PG  4
#define K_SZ  11

#define BX 64              /* out x per block */
#define BY 128             /* out y per block */
#define CHY 16             /* y chunk per staging pass */
#define QROWS 31           /* staged rows = CHY + 15 */
#define QPITCH 84          /* staged quads (u64 per x) per row */
#define QROWB (QPITCH*8)   /* 672 bytes per staged row */
#define NUNIT (QROWS*42)   /* 1302 16B staging units */
#define NU 6               /* ceil(NUNIT/256) */
#define DROWS 91           /* diag-C rows: d+11, d in [-11, 79] */
#define DROWB 88           /* 11 kx * 8B */

typedef _Float16 f16;
typedef __attribute__((ext_vector_type(2))) __fp16 fp16x2;
typedef __attribute__((ext_vector_type(8))) _Float16 f16x8;
typedef __attribute__((ext_vector_type(4))) float f32x4;
typedef unsigned long long u64;

struct alignas(8) H4 { f16 x, y, z, w; };
union H8U { H4 h[2]; uint4 u; };
union U32H2 { unsigned u; fp16x2 h; };

__device__ __forceinline__ fp16x2 h2u(unsigned x) { U32H2 t; t.u = x; return t.h; }

// ---- pack weights into per-lane MFMA A-fragments, quad-plane-0 hole ----
// entry e=t*64+l for (g,s): 16B at byte ((g*2+s)*2048 + 512)*8 + e*16.
__global__ void pack_w_k(const float* __restrict__ weight, u64* __restrict__ qprobs) {
  for (int e = threadIdx.x; e < 1536; e += 256) {
    const int l  = e & 63;
    const int r1 = e >> 6;        // 0..23
    const int t  = r1 % 3;
    const int r2 = r1 / 3;        // 0..7
    const int s  = r2 & 1;
    const int g  = r2 >> 1;
    const int m  = 16 * t + (l & 15);
    const int q  = l >> 4;
    const int kx = m >> 2, co = m & 3;
    f16 vals[8];
#pragma unroll
    for (int j = 0; j < 8; ++j) {
      const int ci = j & 3;
      const int ky = 8 * s + 2 * q + (j >> 2);
      float wv = 0.f;
      if (kx < K_SZ && ky < K_SZ)
        wv = weight[(((size_t)(g * 4 + co) * C_PG + ci) * K_SZ + ky) * K_SZ + kx];
      vals[j] = (f16)wv;
    }
    f16* dst = reinterpret_cast<f16*>(
        reinterpret_cast<char*>(qprobs) +
        ((size_t)(g * 2 + s) * L_DIM + 512) * 8 + (size_t)(t * 64 + l) * 16);
#pragma unroll
    for (int j = 0; j < 8; ++j) dst[j] = vals[j];
  }
}

// ---------------- causal softmax -> channel-quad probs ----------------
__global__ __launch_bounds__(256) void softmax_q_k(
    const float* __restrict__ scores, u64* __restrict__ qprobs) {
  const int bid = blockIdx.x;
  const int zg  = bid & 7;            // (b,g) -> XCD-pinned
  const int y   = bid >> 3;
  const int b   = zg >> 2, g = zg & 3;
  const int tid = threadIdx.x;
  const int w    = tid >> 6;
  const int lane = tid & 63;

  __shared__ float mred[4][4];
  __shared__ float sred[4][4];

  const float* sbase = scores + ((size_t)(b * C_CH + g * 4) * L_DIM + y) * L_DIM;
  const size_t plane = (size_t)L_DIM * L_DIM;

  float v[4][8];
#pragma unroll
  for (int cc = 0; cc < 4; ++cc)
#pragma unroll
    for (int j = 0; j < 4; ++j) {
      const int x = 512 * w + 128 * j + 2 * lane;
      float2 f = make_float2(-INFINITY, -INFINITY);
      if (512 * w + 128 * j <= y) {
        f = *reinterpret_cast<const float2*>(sbase + cc * plane + x);
        if (x > y)     f.x = -INFINITY;
        if (x + 1 > y) f.y = -INFINITY;
      }
      v[cc][2 * j]     = f.x;
      v[cc][2 * j + 1] = f.y;
    }

  float ml[4];
#pragma unroll
  for (int cc = 0; cc < 4; ++cc) {
    float m = v[cc][0];
#pragma unroll
    for (int i = 1; i < 8; ++i) m = fmaxf(m, v[cc][i]);
#pragma unroll
    for (int off = 32; off >= 1; off >>= 1) m = fmaxf(m, __shfl_xor(m, off, 64));
    ml[cc] = m;
  }
  if (lane == 0) {
#pragma unroll
    for (int cc = 0; cc < 4; ++cc) mred[w][cc] = ml[cc];
  }
  __syncthreads();
  float mf[4];
#pragma unroll
  for (int cc = 0; cc < 4; ++cc)
    mf[cc] = fmaxf(fmaxf(mred[0][cc], mred[1][cc]),
                   fmaxf(mred[2][cc], mred[3][cc]));

  float sl[4];
#pragma unroll
  for (int cc = 0; cc < 4; ++cc) {
    float s = 0.f;
#pragma unroll
    for (int i = 0; i < 8; ++i) { v[cc][i] = __expf(v[cc][i] - mf[cc]); s += v[cc][i]; }
#pragma unroll
    for (int off = 32; off >= 1; off >>= 1) s += __shfl_xor(s, off, 64);
    sl[cc] = s;
  }
  if (lane == 0) {
#pragma unroll
    for (int cc = 0; cc < 4; ++cc) sred[w][cc] = sl[cc];
  }
  __syncthreads();
  float inv[4];
#pragma unroll
  for (int cc = 0; cc < 4; ++cc)
    inv[cc] = 1.0f / (sred[0][cc] + sred[1][cc] + sred[2][cc] + sred[3][cc]);

  u64* qrow = qprobs + ((size_t)zg * L_DIM + y) * L_DIM;
#pragma unroll
  for (int j = 0; j < 4; ++j) {
    const int xbase = 512 * w + 128 * j;
    if (xbase > y + 11) continue;
    const int x = xbase + 2 * lane;
    H8U o;
    o.h[0].x = (f16)(v[0][2*j]   * inv[0]);
    o.h[0].y = (f16)(v[1][2*j]   * inv[1]);
    o.h[0].z = (f16)(v[2][2*j]   * inv[2]);
    o.h[0].w = (f16)(v[3][2*j]   * inv[3]);
    o.h[1].x = (f16)(v[0][2*j+1] * inv[0]);
    o.h[1].y = (f16)(v[1][2*j+1] * inv[1]);
    o.h[1].z = (f16)(v[2][2*j+1] * inv[2]);
    o.h[1].w = (f16)(v[3][2*j+1] * inv[3]);
    *reinterpret_cast<uint4*>(qrow + x) = o.u;
  }
}

// ---------------- shift-GEMM grouped conv via f16 MFMA, diag-C epilogue ----
// C[m=4kx+co][xc] computed by MFMA; since reg=co and kx=4t+q, C is written
// straight into diagonal layout [d=xc-kx][kx]{co0..3}; output x reads ONE
// contiguous 88B row (d = x-5) and tree-sums 11 kx terms with v_pk_add_f16.
__global__ __launch_bounds__(256, 3) void conv_k(
    const u64* __restrict__ qprobs, const float* __restrict__ bias,
    float* __restrict__ out) {
  const int bid = blockIdx.x;
  const int zg  = bid & 7;            // (b,g) -> XCD-pinned
  const int lin = bid >> 3;           // 0..511
  const int xt  = lin & 31, yt = lin >> 5;
  const int x0 = xt * BX;
  const int Y0 = yt * BY;
  const int bb = zg >> 2, g = zg & 3;
  const int tid = threadIdx.x;
  const size_t plane = (size_t)L_DIM * L_DIM;

  float* outg = out + (size_t)(bb * C_CH + g * 4) * plane;

  if (x0 >= Y0 + BY) {
    const int co = (tid >> 4) & 3;
    const int xq = tid & 15;
    const float4 z4 = make_float4(0.f, 0.f, 0.f, 0.f);
    for (int r = (tid >> 6); r < BY; r += 4) {
      float* op = outg + (size_t)co * plane + (size_t)(Y0 + r) * L_DIM + x0 + 4 * xq;
      *reinterpret_cast<float4*>(op) = z4;
    }
    return;
  }

  __shared__ u64 Qs[QROWS * QPITCH];       // staged probs (20832 B)
  __shared__ u64 CLd[4 * DROWS * (DROWB/8)];  // diag C, 4 waves (32032 B)

  const int lane = tid & 63;
  const int w    = tid >> 6;
  const int q    = lane >> 4;
  const int c    = lane & 15;

  // A fragments from quad-plane-0 hole
  f16x8 A00, A01, A10, A11, A20, A21;
  {
    const char* qp0 = reinterpret_cast<const char*>(qprobs);
    const char* at0 = qp0 + ((size_t)(g * 2 + 0) * L_DIM + 512) * 8;
    const char* at1 = qp0 + ((size_t)(g * 2 + 1) * L_DIM + 512) * 8;
    A00 = *reinterpret_cast<const f16x8*>(at0 + (0 * 64 + lane) * 16);
    A10 = *reinterpret_cast<const f16x8*>(at0 + (1 * 64 + lane) * 16);
    A20 = *reinterpret_cast<const f16x8*>(at0 + (2 * 64 + lane) * 16);
    A01 = *reinterpret_cast<const f16x8*>(at1 + (0 * 64 + lane) * 16);
    A11 = *reinterpret_cast<const f16x8*>(at1 + (1 * 64 + lane) * 16);
    A21 = *reinterpret_cast<const f16x8*>(at1 + (2 * 64 + lane) * 16);
  }

  const float bs0 = bias[g * 4 + 0], bs1 = bias[g * 4 + 1];
  const float bs2 = bias[g * 4 + 2], bs3 = bias[g * 4 + 3];

  const u64* qplane = qprobs + (size_t)zg * plane;
  const int qx0 = x0 - 8;

  char* const qbase = reinterpret_cast<char*>(Qs);
  char* const clw   = reinterpret_cast<char*>(CLd) + w * (DROWS * DROWB);
  const char* const qlane = qbase + q * 1344 + c * 8;
  // diag write base: row = (c - q + 11) + 16xs - 4t, col byte = (4t+q)*8
  char* const cw = clw + (c - q + 11) * DROWB + q * 8;
  // diag read base: row = lane + 14 (d = lane+3)
  const char* const ce = clw + (lane + 14) * DROWB;

  for (int cb = Y0; cb < Y0 + BY; cb += CHY) {
    if (x0 > cb + CHY - 1) {
      const int co = (tid >> 4) & 3;
      const int xq = tid & 15;
      const float4 z4 = make_float4(0.f, 0.f, 0.f, 0.f);
      for (int r = (tid >> 6); r < CHY; r += 4) {
        float* op = outg + (size_t)co * plane + (size_t)(cb + r) * L_DIM + x0 + 4 * xq;
        *reinterpret_cast<float4*>(op) = z4;
      }
      continue;
    }

    // phase 1: issue all staging loads
    uint4 sv[NU];
#pragma unroll
    for (int k = 0; k < NU; ++k) {
      const int u   = tid + 256 * k;
      const int r   = u / 42;
      const int c16 = u - 42 * r;
      const int py  = cb - 5 + r;
      const int qc0 = qx0 + 2 * c16;
      sv[k] = make_uint4(0u, 0u, 0u, 0u);
      if (u < NUNIT && py >= 0 && py < L_DIM && qc0 >= 0 && qc0 <= L_DIM - 2)
        sv[k] = *reinterpret_cast<const uint4*>(qplane + (size_t)py * L_DIM + qc0);
    }
    __syncthreads();
    // phase 2: LDS write
#pragma unroll
    for (int k = 0; k < NU; ++k) {
      const int u = tid + 256 * k;
      if (u < NUNIT) {
        const int r   = u / 42;
        const int c16 = u - 42 * r;
        *reinterpret_cast<uint4*>(qbase + r * QROWB + c16 * 16) = sv[k];
      }
    }
    __syncthreads();

    for (int i = 0; i < CHY / 4; ++i) {
      const int y = cb + w * (CHY / 4) + i;   // wave-uniform
      float* orow = outg + (size_t)y * L_DIM + x0 + lane;
      if (y < x0) {
        orow[0] = 0.f; orow[plane] = 0.f;
        orow[2 * plane] = 0.f; orow[3 * plane] = 0.f;
        continue;
      }
      const char* qy = qlane + (y - cb) * QROWB;

      u64 b00[5], b01[5], b10[5], b11[5];
#pragma unroll
      for (int xs = 0; xs < 5; ++xs) {
        b00[xs] = *reinterpret_cast<const u64*>(qy + xs * 128 + 0);
        b01[xs] = *reinterpret_cast<const u64*>(qy + xs * 128 + 672);
        b10[xs] = *reinterpret_cast<const u64*>(qy + xs * 128 + 5376);
        b11[xs] = *reinterpret_cast<const u64*>(qy + xs * 128 + 6048);
      }

      __builtin_amdgcn_s_setprio(1);
#pragma unroll
      for (int xs = 0; xs < 5; ++xs) {
        union { u64 u[2]; f16x8 v; } B0, B1;
        B0.u[0] = b00[xs]; B0.u[1] = b01[xs];
        B1.u[0] = b10[xs]; B1.u[1] = b11[xs];
        f32x4 z = {0.f, 0.f, 0.f, 0.f};
        f32x4 c0 = __builtin_amdgcn_mfma_f32_16x16x32_f16(A00, B0.v, z, 0, 0, 0);
        c0 = __builtin_amdgcn_mfma_f32_16x16x32_f16(A01, B1.v, c0, 0, 0, 0);
        f32x4 c1 = __builtin_amdgcn_mfma_f32_16x16x32_f16(A10, B0.v, z, 0, 0, 0);
        c1 = __builtin_amdgcn_mfma_f32_16x16x32_f16(A11, B1.v, c1, 0, 0, 0);
        f32x4 c2 = __builtin_amdgcn_mfma_f32_16x16x32_f16(A20, B0.v, z, 0, 0, 0);
        c2 = __builtin_amdgcn_mfma_f32_16x16x32_f16(A21, B1.v, c2, 0, 0, 0);

        union { fp16x2 h[2]; u64 u; } pk;
        pk.h[0] = __builtin_amdgcn_cvt_pkrtz(c0[0], c0[1]);
        pk.h[1] = __builtin_amdgcn_cvt_pkrtz(c0[2], c0[3]);
        *reinterpret_cast<u64*>(cw + xs * 1408 + 0)   = pk.u;       // t=0, kx=q
        pk.h[0] = __builtin_amdgcn_cvt_pkrtz(c1[0], c1[1]);
        pk.h[1] = __builtin_amdgcn_cvt_pkrtz(c1[2], c1[3]);
        *reinterpret_cast<u64*>(cw + xs * 1408 - 320) = pk.u;       // t=1, kx=4+q
        if (q != 3) {                                               // kx=8+q <= 10
          pk.h[0] = __builtin_amdgcn_cvt_pkrtz(c2[0], c2[1]);
          pk.h[1] = __builtin_amdgcn_cvt_pkrtz(c2[2], c2[3]);
          *reinterpret_cast<u64*>(cw + xs * 1408 - 640) = pk.u;     // t=2
        }
      }
      __builtin_amdgcn_s_setprio(0);

      // epilogue: one contiguous 88B row, f16x2 tree sum over 11 kx
      const uint4 r0 = *reinterpret_cast<const uint4*>(ce + 0);
      const uint4 r1 = *reinterpret_cast<const uint4*>(ce + 16);
      const uint4 r2 = *reinterpret_cast<const uint4*>(ce + 32);
      const uint4 r3 = *reinterpret_cast<const uint4*>(ce + 48);
      const uint4 r4 = *reinterpret_cast<const uint4*>(ce + 64);
      const uint2 r5 = *reinterpret_cast<const uint2*>(ce + 80);
      fp16x2 e01 = (h2u(r0.x) + h2u(r0.z)) + (h2u(r1.x) + h2u(r1.z));
      fp16x2 f01 = (h2u(r2.x) + h2u(r2.z)) + (h2u(r3.x) + h2u(r3.z));
      fp16x2 g01 = (h2u(r4.x) + h2u(r4.z)) + h2u(r5.x);
      e01 = (e01 + f01) + g01;
      fp16x2 e23 = (h2u(r0.y) + h2u(r0.w)) + (h2u(r1.y) + h2u(r1.w));
      fp16x2 f23 = (h2u(r2.y) + h2u(r2.w)) + (h2u(r3.y) + h2u(r3.w));
      fp16x2 g23 = (h2u(r4.y) + h2u(r4.w)) + h2u(r5.y);
      e23 = (e23 + f23) + g23;

      const bool act = (x0 + lane) <= y;
      orow[0]         = act ? (float)e01[0] + bs0 : 0.f;
      orow[plane]     = act ? (float)e01[1] + bs1 : 0.f;
      orow[2 * plane] = act ? (float)e23[0] + bs2 : 0.f;
      orow[3 * plane] = act ? (float)e23[1] + bs3 : 0.f;
    }
  }
}

extern "C" void kernel_launch(void* const* d_in, const int* in_sizes, int n_in,
                              void* d_out, int out_size, void* d_ws, size_t ws_size,
                              hipStream_t stream) {
  const float* scores = (const float*)d_in[0];
  const float* weight = (const float*)d_in[1];
  const float* bias   = (const float*)d_in[2];
  float* outp = (float*)d_out;
  u64* qprobs = (u64*)d_ws;   // B*G*L*L u64 quads = 256 MB (+ A-table hole)

  pack_w_k<<<1, 256, 0, stream>>>(weight, qprobs);

  softmax_q_k<<<B_SZ * N_G * L_DIM, 256, 0, stream>>>(scores, qprobs);

  conv_k<<<(L_DIM / BX) * (L_DIM / BY) * B_SZ * N_G, 256, 0, stream>>>(
      qprobs, bias, outp);
}